// Round 1
// baseline (438.926 us; speedup 1.0000x reference)
//
#include <hip/hip_runtime.h>
#include <hip/hip_bf16.h>

#define Hdim 64
#define NDIAG 10000
#define NEDGE 1000000
#define NINST 500000

// ---------------- histogram of destination degrees ----------------
__global__ void hist_kernel(const int* __restrict__ b2d_dst, const int* __restrict__ t2d_dst,
                            int* __restrict__ deg_b, int* __restrict__ deg_t) {
    int stride = gridDim.x * blockDim.x;
    for (int e = blockIdx.x * blockDim.x + threadIdx.x; e < 2 * NEDGE; e += stride) {
        if (e < NEDGE) atomicAdd(&deg_b[b2d_dst[e]], 1);
        else           atomicAdd(&deg_t[t2d_dst[e - NEDGE]], 1);
    }
}

// ---------------- exclusive scan (block 0: bene, block 1: treat) ----------------
__global__ void scan_kernel(const int* __restrict__ deg_b, int* __restrict__ off_b, int* __restrict__ cur_b,
                            const int* __restrict__ deg_t, int* __restrict__ off_t, int* __restrict__ cur_t) {
    const int* deg = (blockIdx.x == 0) ? deg_b : deg_t;
    int* off = (blockIdx.x == 0) ? off_b : off_t;
    int* cur = (blockIdx.x == 0) ? cur_b : cur_t;
    __shared__ int partial[256];
    const int CHUNK = (NDIAG + 255) / 256;   // 40
    int t = threadIdx.x;
    int start = t * CHUNK;
    int s = 0;
    for (int i = 0; i < CHUNK; ++i) {
        int j = start + i;
        if (j < NDIAG) s += deg[j];
    }
    partial[t] = s;
    __syncthreads();
    for (int o = 1; o < 256; o <<= 1) {
        int v = (t >= o) ? partial[t - o] : 0;
        __syncthreads();
        partial[t] += v;
        __syncthreads();
    }
    int run = (t == 0) ? 0 : partial[t - 1];
    for (int i = 0; i < CHUNK; ++i) {
        int j = start + i;
        if (j < NDIAG) { off[j] = run; cur[j] = run; run += deg[j]; }
    }
    if (t == 255) off[NDIAG] = partial[255];
}

// ---------------- scatter composed source-embedding-row indices into CSR ----------------
__global__ void scatter_kernel(const int* __restrict__ b2d_src, const int* __restrict__ b2d_dst,
                               const int* __restrict__ bene_ids,
                               const int* __restrict__ t2d_src, const int* __restrict__ t2d_dst,
                               const int* __restrict__ treat_ids,
                               int* __restrict__ cur_b, int* __restrict__ csr_b,
                               int* __restrict__ cur_t, int* __restrict__ csr_t) {
    int stride = gridDim.x * blockDim.x;
    for (int e = blockIdx.x * blockDim.x + threadIdx.x; e < 2 * NEDGE; e += stride) {
        if (e < NEDGE) {
            int d = b2d_dst[e];
            int p = atomicAdd(&cur_b[d], 1);
            csr_b[p] = bene_ids[b2d_src[e]];
        } else {
            int e2 = e - NEDGE;
            int d = t2d_dst[e2];
            int p = atomicAdd(&cur_t[d], 1);
            csr_t[p] = treat_ids[t2d_src[e2]];
        }
    }
}

// ---------------- per-diag aggregation + layer-1 conv + output MLP + sigmoid ----------------
// one 64-lane wave per diag node; lane = feature dim
__global__ __launch_bounds__(256) void diag_kernel(
    const float* __restrict__ bene_emb, const float* __restrict__ treat_emb,
    const int* __restrict__ off_b, const int* __restrict__ csr_b,
    const int* __restrict__ off_t, const int* __restrict__ csr_t,
    const float* __restrict__ Wb1, const float* __restrict__ bb1,
    const float* __restrict__ Wt1, const float* __restrict__ bt1,
    const float* __restrict__ Wu1, const float* __restrict__ bu1,
    const float* __restrict__ oW1, const float* __restrict__ ob1,
    const float* __restrict__ oW2, const float* __restrict__ ob2,
    float* __restrict__ per_diag_out) {
    int wave = threadIdx.x >> 6;
    int lane = threadIdx.x & 63;
    int d = blockIdx.x * 4 + wave;

    __shared__ float Sb[4][64];
    __shared__ float St[4][64];
    __shared__ float Cc[4][64];
    __shared__ float Dd[4][64];

    // ---- segment sums of relu'd embedding rows (layer-1 features) ----
    float sb = 0.f, st = 0.f;
    int s0 = off_b[d], s1 = off_b[d + 1];
    int j = s0;
    for (; j + 4 <= s1; j += 4) {
        int i0 = csr_b[j], i1 = csr_b[j + 1], i2 = csr_b[j + 2], i3 = csr_b[j + 3];
        float v0 = bene_emb[i0 * Hdim + lane];
        float v1 = bene_emb[i1 * Hdim + lane];
        float v2 = bene_emb[i2 * Hdim + lane];
        float v3 = bene_emb[i3 * Hdim + lane];
        sb += fmaxf(v0, 0.f) + fmaxf(v1, 0.f) + fmaxf(v2, 0.f) + fmaxf(v3, 0.f);
    }
    for (; j < s1; ++j) sb += fmaxf(bene_emb[csr_b[j] * Hdim + lane], 0.f);

    int t0 = off_t[d], t1 = off_t[d + 1];
    j = t0;
    for (; j + 4 <= t1; j += 4) {
        int i0 = csr_t[j], i1 = csr_t[j + 1], i2 = csr_t[j + 2], i3 = csr_t[j + 3];
        float v0 = treat_emb[i0 * Hdim + lane];
        float v1 = treat_emb[i1 * Hdim + lane];
        float v2 = treat_emb[i2 * Hdim + lane];
        float v3 = treat_emb[i3 * Hdim + lane];
        st += fmaxf(v0, 0.f) + fmaxf(v1, 0.f) + fmaxf(v2, 0.f) + fmaxf(v3, 0.f);
    }
    for (; j < t1; ++j) st += fmaxf(treat_emb[csr_t[j] * Hdim + lane], 0.f);

    Sb[wave][lane] = sb;
    St[wave][lane] = st;
    __syncthreads();

    // ---- agg_b = S_b @ Wb1 + deg_b*bb1 ; agg_t = S_t @ Wt1 + deg_t*bt1 ----
    float degb = (float)(s1 - s0), degt = (float)(t1 - t0);
    float ab = degb * bb1[lane];
    float at = degt * bt1[lane];
    #pragma unroll 8
    for (int l = 0; l < Hdim; ++l) {
        ab += Sb[wave][l] * Wb1[l * Hdim + lane];
        at += St[wave][l] * Wt1[l * Hdim + lane];
    }
    float comb = 0.5f * (ab + at);
    Cc[wave][lane] = comb;
    __syncthreads();

    // ---- diag1 = combined @ Wu1 + bu1 ; relu ----
    float dg = bu1[lane];
    #pragma unroll 8
    for (int l = 0; l < Hdim; ++l) dg += Cc[wave][l] * Wu1[l * Hdim + lane];
    float d1 = fmaxf(dg, 0.f);
    Dd[wave][lane] = d1;
    __syncthreads();

    // ---- h = relu(d1 @ oW1 + ob1) (64->32); logit = h @ oW2 + ob2; sigmoid ----
    float contrib = 0.f;
    if (lane < 32) {
        float h = ob1[lane];
        #pragma unroll 8
        for (int l = 0; l < Hdim; ++l) h += Dd[wave][l] * oW1[l * 32 + lane];
        h = fmaxf(h, 0.f);
        contrib = h * oW2[lane];
    }
    for (int o = 32; o > 0; o >>= 1) contrib += __shfl_down(contrib, o);
    if (lane == 0) {
        float logit = contrib + ob2[0];
        per_diag_out[d] = 1.f / (1.f + __expf(-logit));
    }
}

// ---------------- final instance gather ----------------
__global__ void gather_kernel(const int* __restrict__ inst2type,
                              const float* __restrict__ per_diag_out,
                              float* __restrict__ out) {
    int i = blockIdx.x * blockDim.x + threadIdx.x;
    int i4 = i * 4;
    if (i4 >= NINST) return;
    int4 t = *reinterpret_cast<const int4*>(inst2type + i4);
    float4 r;
    r.x = per_diag_out[t.x];
    r.y = per_diag_out[t.y];
    r.z = per_diag_out[t.z];
    r.w = per_diag_out[t.w];
    *reinterpret_cast<float4*>(out + i4) = r;
}

extern "C" void kernel_launch(void* const* d_in, const int* in_sizes, int n_in,
                              void* d_out, int out_size, void* d_ws, size_t ws_size,
                              hipStream_t stream) {
    (void)in_sizes; (void)n_in; (void)out_size; (void)ws_size;

    const int*   bene_ids  = (const int*)d_in[0];
    // d_in[1] diag_ids: dead (unused by reference)
    const int*   treat_ids = (const int*)d_in[2];
    const int*   b2d_src   = (const int*)d_in[3];
    const int*   b2d_dst   = (const int*)d_in[4];
    const int*   t2d_src   = (const int*)d_in[5];
    const int*   t2d_dst   = (const int*)d_in[6];
    const int*   inst2type = (const int*)d_in[7];
    const float* bene_emb  = (const float*)d_in[8];
    // d_in[9] diag_emb: dead
    const float* treat_emb = (const float*)d_in[10];
    // d_in[11..16] layer-0 weights: dead (conv0 output is never consumed)
    const float* Wb1 = (const float*)d_in[17];
    const float* bb1 = (const float*)d_in[18];
    const float* Wt1 = (const float*)d_in[19];
    const float* bt1 = (const float*)d_in[20];
    const float* Wu1 = (const float*)d_in[21];
    const float* bu1 = (const float*)d_in[22];
    const float* oW1 = (const float*)d_in[23];
    const float* ob1 = (const float*)d_in[24];
    const float* oW2 = (const float*)d_in[25];
    const float* ob2 = (const float*)d_in[26];
    float* out = (float*)d_out;

    // ---- workspace carve-up (256B-aligned regions) ----
    char* w = (char*)d_ws;
    auto alloc = [&](size_t bytes) {
        char* p = w;
        w += (bytes + 255) & ~(size_t)255;
        return p;
    };
    int* deg_b = (int*)alloc(NDIAG * 4);
    int* deg_t = (int*)alloc(NDIAG * 4);
    int* off_b = (int*)alloc((NDIAG + 1) * 4);
    int* off_t = (int*)alloc((NDIAG + 1) * 4);
    int* cur_b = (int*)alloc(NDIAG * 4);
    int* cur_t = (int*)alloc(NDIAG * 4);
    int* csr_b = (int*)alloc((size_t)NEDGE * 4);
    int* csr_t = (int*)alloc((size_t)NEDGE * 4);
    float* pdo = (float*)alloc(NDIAG * 4);

    // zero the degree histograms (deg_b and deg_t are adjacent regions)
    hipMemsetAsync(deg_b, 0, (size_t)((char*)deg_t - (char*)deg_b) + NDIAG * 4, stream);

    hist_kernel<<<2048, 256, 0, stream>>>(b2d_dst, t2d_dst, deg_b, deg_t);
    scan_kernel<<<2, 256, 0, stream>>>(deg_b, off_b, cur_b, deg_t, off_t, cur_t);
    scatter_kernel<<<2048, 256, 0, stream>>>(b2d_src, b2d_dst, bene_ids,
                                             t2d_src, t2d_dst, treat_ids,
                                             cur_b, csr_b, cur_t, csr_t);
    diag_kernel<<<NDIAG / 4, 256, 0, stream>>>(bene_emb, treat_emb,
                                               off_b, csr_b, off_t, csr_t,
                                               Wb1, bb1, Wt1, bt1, Wu1, bu1,
                                               oW1, ob1, oW2, ob2, pdo);
    gather_kernel<<<(NINST / 4 + 255) / 256, 256, 0, stream>>>(inst2type, pdo, out);
}